// Round 1
// baseline (476.763 us; speedup 1.0000x reference)
//
#include <hip/hip_runtime.h>
#include <hip/hip_bf16.h>

// Problem constants (shapes from reference): in_f = out_f = 128.
#define F 128
#define TM 32            // rows per block in node GEMM
#define NEG_SLOPE 0.01f

// ---------------------------------------------------------------------------
// Kernel A: per-node GEMM  Y = src_h @ W + b   (N x 128)
// fused epilogue: yz[n] = Y[n] . attn_W[0:128]
//                 ss[n] = self_h[n] . attn_W[128:256]
// Block: 256 threads = 8 rowgroups x 32 colgroups; each thread: 4 rows x 4 cols.
// ---------------------------------------------------------------------------
__global__ __launch_bounds__(256) void node_kernel(
    const float* __restrict__ src_h,   // [N,128]
    const float* __restrict__ self_h,  // [N,128]
    const float* __restrict__ W,       // [128,128]
    const float* __restrict__ b,       // [128]
    const float* __restrict__ attn_W,  // [256]
    float* __restrict__ Y,             // [N,128] (ws)
    float* __restrict__ yz,            // [N]     (ws)
    float* __restrict__ ss,            // [N]     (ws)
    int N)
{
    __shared__ float Wl[F * F];        // 64 KB
    __shared__ float Al[TM * F];       // 16 KB

    const int t = threadIdx.x;
    const int row0 = blockIdx.x * TM;

    // Stage W into LDS: 16384 floats, 256 threads x 16 float4
    for (int i = t * 4; i < F * F; i += 256 * 4) {
        *(float4*)&Wl[i] = *(const float4*)&W[i];
    }
    // Stage A tile (TM x 128): 1024 float4, 4 per thread
    for (int i = t; i < TM * F / 4; i += 256) {
        const int r  = i >> 5;          // / (F/4)
        const int c4 = i & 31;          // % (F/4)
        const int gr = row0 + r;
        float4 v = make_float4(0.f, 0.f, 0.f, 0.f);
        if (gr < N) v = *(const float4*)&src_h[(size_t)gr * F + c4 * 4];
        *(float4*)&Al[r * F + c4 * 4] = v;
    }
    __syncthreads();

    const int colgrp = t & 31;         // 0..31
    const int rowgrp = t >> 5;         // 0..7
    const int c0 = colgrp * 4;
    const int r0 = rowgrp * 4;

    float acc[4][4] = {};

    #pragma unroll 4
    for (int k = 0; k < F; k += 4) {
        const float4 w0 = *(const float4*)&Wl[(k + 0) * F + c0];
        const float4 w1 = *(const float4*)&Wl[(k + 1) * F + c0];
        const float4 w2 = *(const float4*)&Wl[(k + 2) * F + c0];
        const float4 w3 = *(const float4*)&Wl[(k + 3) * F + c0];
        #pragma unroll
        for (int i = 0; i < 4; i++) {
            const float4 a = *(const float4*)&Al[(r0 + i) * F + k];
            acc[i][0] += a.x * w0.x + a.y * w1.x + a.z * w2.x + a.w * w3.x;
            acc[i][1] += a.x * w0.y + a.y * w1.y + a.z * w2.y + a.w * w3.y;
            acc[i][2] += a.x * w0.z + a.y * w1.z + a.z * w2.z + a.w * w3.z;
            acc[i][3] += a.x * w0.w + a.y * w1.w + a.z * w2.w + a.w * w3.w;
        }
    }

    // Epilogue: bias, store Y, reduce yz and ss
    const float4 bb  = *(const float4*)&b[c0];
    const float4 waz = *(const float4*)&attn_W[c0];        // Wa_z slice
    const float4 was = *(const float4*)&attn_W[F + c0];    // Wa_s slice

    #pragma unroll
    for (int i = 0; i < 4; i++) {
        const int gr = row0 + r0 + i;
        float4 o;
        o.x = acc[i][0] + bb.x;
        o.y = acc[i][1] + bb.y;
        o.z = acc[i][2] + bb.z;
        o.w = acc[i][3] + bb.w;

        // yz partial for this row
        float pz = o.x * waz.x + o.y * waz.y + o.z * waz.z + o.w * waz.w;

        // ss partial for this row (read self_h coalesced)
        float ps = 0.f;
        if (gr < N) {
            const float4 s = *(const float4*)&self_h[(size_t)gr * F + c0];
            ps = s.x * was.x + s.y * was.y + s.z * was.z + s.w * was.w;
        }

        // reduce across the 32 colgroups (lanes 0..31 / 32..63 of the wave)
        #pragma unroll
        for (int m = 16; m >= 1; m >>= 1) {
            pz += __shfl_xor(pz, m, 32);
            ps += __shfl_xor(ps, m, 32);
        }

        if (gr < N) {
            *(float4*)&Y[(size_t)gr * F + c0] = o;
            if (colgrp == 0) {
                yz[gr] = pz;
                ss[gr] = ps;
            }
        }
    }
}

// ---------------------------------------------------------------------------
// Kernel B: per-edge gather + logit.
// 32 lanes per edge: float4 row copy Y[src] -> z1[e]; lane 0 computes e_out.
// 8 edges per 256-thread block; consecutive edges -> contiguous 4 KB writes.
// ---------------------------------------------------------------------------
__global__ __launch_bounds__(256) void edge_kernel(
    const int* __restrict__ src_idx,
    const int* __restrict__ dst_idx,
    const float* __restrict__ Y,
    const float* __restrict__ yz,
    const float* __restrict__ ss,
    const float* __restrict__ attn_b,
    float* __restrict__ z1,            // [E,128]
    float* __restrict__ e_out,         // [E]
    int E)
{
    const int t = threadIdx.x;
    const int e = blockIdx.x * 8 + (t >> 5);
    if (e >= E) return;
    const int lane = t & 31;

    const int s = src_idx[e];
    const float4 v = *(const float4*)&Y[(size_t)s * F + lane * 4];
    *(float4*)&z1[(size_t)e * F + lane * 4] = v;

    if (lane == 0) {
        const int d = dst_idx[e];
        const float a = yz[s] + ss[d] + attn_b[0];
        e_out[e] = (a >= 0.f) ? a : NEG_SLOPE * a;
    }
}

extern "C" void kernel_launch(void* const* d_in, const int* in_sizes, int n_in,
                              void* d_out, int out_size, void* d_ws, size_t ws_size,
                              hipStream_t stream)
{
    const float* src_h  = (const float*)d_in[0];
    const float* self_h = (const float*)d_in[1];
    const int*   src_idx = (const int*)d_in[2];
    const int*   dst_idx = (const int*)d_in[3];
    const float* W      = (const float*)d_in[4];
    const float* b      = (const float*)d_in[5];
    const float* attn_W = (const float*)d_in[6];
    const float* attn_b = (const float*)d_in[7];

    const int N = in_sizes[0] / F;     // 50000
    const int E = in_sizes[2];         // 600000

    float* z1    = (float*)d_out;                      // [E,128]
    float* e_out = (float*)d_out + (size_t)E * F;      // [E]

    float* Y  = (float*)d_ws;                          // [N,128]
    float* yz = Y + (size_t)N * F;                     // [N]
    float* ss = yz + N;                                // [N]

    node_kernel<<<dim3((N + TM - 1) / TM), 256, 0, stream>>>(
        src_h, self_h, W, b, attn_W, Y, yz, ss, N);

    edge_kernel<<<dim3((E + 7) / 8), 256, 0, stream>>>(
        src_idx, dst_idx, Y, yz, ss, attn_b, z1, e_out, E);
}

// Round 3
// 461.186 us; speedup vs baseline: 1.0338x; 1.0338x over previous
//
#include <hip/hip_runtime.h>
#include <hip/hip_bf16.h>

// Problem constants (shapes from reference): in_f = out_f = 128.
#define F 128
#define TM 32            // rows per block in node GEMM
#define NEG_SLOPE 0.01f

// Native clang vector type — required by __builtin_nontemporal_store
// (HIP's float4 is a class type the builtin rejects).
typedef float vfloat4 __attribute__((ext_vector_type(4)));

// ---------------------------------------------------------------------------
// Kernel A: per-node GEMM  Y = src_h @ W + b   (N x 128)
// fused epilogue: yz[n] = Y[n] . attn_W[0:128]
//                 ss[n] = self_h[n] . attn_W[128:256]
// Block: 256 threads = 8 rowgroups x 32 colgroups; each thread: 4 rows x 4 cols.
// (unchanged — control)
// ---------------------------------------------------------------------------
__global__ __launch_bounds__(256) void node_kernel(
    const float* __restrict__ src_h,   // [N,128]
    const float* __restrict__ self_h,  // [N,128]
    const float* __restrict__ W,       // [128,128]
    const float* __restrict__ b,       // [128]
    const float* __restrict__ attn_W,  // [256]
    float* __restrict__ Y,             // [N,128] (ws)
    float* __restrict__ yz,            // [N]     (ws)
    float* __restrict__ ss,            // [N]     (ws)
    int N)
{
    __shared__ float Wl[F * F];        // 64 KB
    __shared__ float Al[TM * F];       // 16 KB

    const int t = threadIdx.x;
    const int row0 = blockIdx.x * TM;

    // Stage W into LDS: 16384 floats, 256 threads x 16 float4
    for (int i = t * 4; i < F * F; i += 256 * 4) {
        *(float4*)&Wl[i] = *(const float4*)&W[i];
    }
    // Stage A tile (TM x 128): 1024 float4, 4 per thread
    for (int i = t; i < TM * F / 4; i += 256) {
        const int r  = i >> 5;          // / (F/4)
        const int c4 = i & 31;          // % (F/4)
        const int gr = row0 + r;
        float4 v = make_float4(0.f, 0.f, 0.f, 0.f);
        if (gr < N) v = *(const float4*)&src_h[(size_t)gr * F + c4 * 4];
        *(float4*)&Al[r * F + c4 * 4] = v;
    }
    __syncthreads();

    const int colgrp = t & 31;         // 0..31
    const int rowgrp = t >> 5;         // 0..7
    const int c0 = colgrp * 4;
    const int r0 = rowgrp * 4;

    float acc[4][4] = {};

    #pragma unroll 4
    for (int k = 0; k < F; k += 4) {
        const float4 w0 = *(const float4*)&Wl[(k + 0) * F + c0];
        const float4 w1 = *(const float4*)&Wl[(k + 1) * F + c0];
        const float4 w2 = *(const float4*)&Wl[(k + 2) * F + c0];
        const float4 w3 = *(const float4*)&Wl[(k + 3) * F + c0];
        #pragma unroll
        for (int i = 0; i < 4; i++) {
            const float4 a = *(const float4*)&Al[(r0 + i) * F + k];
            acc[i][0] += a.x * w0.x + a.y * w1.x + a.z * w2.x + a.w * w3.x;
            acc[i][1] += a.x * w0.y + a.y * w1.y + a.z * w2.y + a.w * w3.y;
            acc[i][2] += a.x * w0.z + a.y * w1.z + a.z * w2.z + a.w * w3.z;
            acc[i][3] += a.x * w0.w + a.y * w1.w + a.z * w2.w + a.w * w3.w;
        }
    }

    // Epilogue: bias, store Y, reduce yz and ss
    const float4 bb  = *(const float4*)&b[c0];
    const float4 waz = *(const float4*)&attn_W[c0];        // Wa_z slice
    const float4 was = *(const float4*)&attn_W[F + c0];    // Wa_s slice

    #pragma unroll
    for (int i = 0; i < 4; i++) {
        const int gr = row0 + r0 + i;
        float4 o;
        o.x = acc[i][0] + bb.x;
        o.y = acc[i][1] + bb.y;
        o.z = acc[i][2] + bb.z;
        o.w = acc[i][3] + bb.w;

        // yz partial for this row
        float pz = o.x * waz.x + o.y * waz.y + o.z * waz.z + o.w * waz.w;

        // ss partial for this row (read self_h coalesced)
        float ps = 0.f;
        if (gr < N) {
            const float4 s = *(const float4*)&self_h[(size_t)gr * F + c0];
            ps = s.x * was.x + s.y * was.y + s.z * was.z + s.w * was.w;
        }

        // reduce across the 32 colgroups
        #pragma unroll
        for (int m = 16; m >= 1; m >>= 1) {
            pz += __shfl_xor(pz, m, 32);
            ps += __shfl_xor(ps, m, 32);
        }

        if (gr < N) {
            *(float4*)&Y[(size_t)gr * F + c0] = o;
            if (colgrp == 0) {
                yz[gr] = pz;
                ss[gr] = ps;
            }
        }
    }
}

// ---------------------------------------------------------------------------
// Kernel B v2: per-edge gather + logit, grid-stride, nontemporal z1 stores.
// 32 lanes per edge-slot; 8 slots per 256-thread block; fixed grid of 2048
// blocks (8 blocks/CU -> 32 waves/CU). Consecutive groups handle consecutive
// edges each iteration -> contiguous 4 KB store per block per iteration.
// z1 is write-once/never-read: NT stores keep Y resident in L2/L3 for the
// random gathers instead of being thrashed by 309 MB of streaming writes.
// ---------------------------------------------------------------------------
#define EDGE_BLOCKS 2048

__global__ __launch_bounds__(256) void edge_kernel(
    const int* __restrict__ src_idx,
    const int* __restrict__ dst_idx,
    const float* __restrict__ Y,
    const float* __restrict__ yz,
    const float* __restrict__ ss,
    const float* __restrict__ attn_b,
    float* __restrict__ z1,            // [E,128]
    float* __restrict__ e_out,         // [E]
    int E)
{
    const int lane = threadIdx.x & 31;
    const int g    = blockIdx.x * 8 + (threadIdx.x >> 5);  // group id
    const int nG   = EDGE_BLOCKS * 8;                      // total groups
    const float ab = attn_b[0];

    for (int e = g; e < E; e += nG) {
        const int s = src_idx[e];
        const vfloat4 v = *(const vfloat4*)&Y[(size_t)s * F + lane * 4];
        __builtin_nontemporal_store(v, (vfloat4*)&z1[(size_t)e * F + lane * 4]);

        if (lane == 0) {
            const int d = dst_idx[e];
            const float a = yz[s] + ss[d] + ab;
            __builtin_nontemporal_store((a >= 0.f) ? a : NEG_SLOPE * a,
                                        &e_out[e]);
        }
    }
}

extern "C" void kernel_launch(void* const* d_in, const int* in_sizes, int n_in,
                              void* d_out, int out_size, void* d_ws, size_t ws_size,
                              hipStream_t stream)
{
    const float* src_h  = (const float*)d_in[0];
    const float* self_h = (const float*)d_in[1];
    const int*   src_idx = (const int*)d_in[2];
    const int*   dst_idx = (const int*)d_in[3];
    const float* W      = (const float*)d_in[4];
    const float* b      = (const float*)d_in[5];
    const float* attn_W = (const float*)d_in[6];
    const float* attn_b = (const float*)d_in[7];

    const int N = in_sizes[0] / F;     // 50000
    const int E = in_sizes[2];         // 600000

    float* z1    = (float*)d_out;                      // [E,128]
    float* e_out = (float*)d_out + (size_t)E * F;      // [E]

    float* Y  = (float*)d_ws;                          // [N,128]
    float* yz = Y + (size_t)N * F;                     // [N]
    float* ss = yz + N;                                // [N]

    node_kernel<<<dim3((N + TM - 1) / TM), 256, 0, stream>>>(
        src_h, self_h, W, b, attn_W, Y, yz, ss, N);

    edge_kernel<<<dim3(EDGE_BLOCKS), 256, 0, stream>>>(
        src_idx, dst_idx, Y, yz, ss, attn_b, z1, e_out, E);
}